// Round 1
// baseline (259.288 us; speedup 1.0000x reference)
//
#include <hip/hip_runtime.h>

#define NU 8192
#define NI 8192
#define DD 128

typedef float fx4 __attribute__((ext_vector_type(4)));
typedef int   ix4 __attribute__((ext_vector_type(4)));
typedef short bx8 __attribute__((ext_vector_type(8)));
typedef short sx4 __attribute__((ext_vector_type(4)));

__device__ __forceinline__ short f2bf(float f) {
  unsigned u = __float_as_uint(f);
  u = (u + 0x7FFFu + ((u >> 16) & 1u)) >> 16;   // RNE f32 -> bf16
  return (short)u;
}

__device__ __forceinline__ float lrelu(float x) { return fmaxf(x, 0.2f * x); }

// ---- K1: v1[j] = sum_k a[k]*W[k][j] ; v2[j] = sum_k a[128+k]*W[k][j]
__global__ void k_vecs(const float* __restrict__ W, const float* __restrict__ a,
                       float* __restrict__ v1, float* __restrict__ v2) {
  int j = threadIdx.x;  // 128 threads
  float s1 = 0.f, s2 = 0.f;
  for (int k = 0; k < DD; ++k) {
    float w = W[k * DD + j];
    s1 += a[k] * w;
    s2 += a[DD + k] * w;
  }
  v1[j] = s1; v2[j] = s2;
}

// ---- K2: a1[u] = h_u[u]·v1 ; a2[i] = h_i[i]·v2
__global__ void k_rowdots(const float* __restrict__ hU, const float* __restrict__ hI,
                          const float* __restrict__ v1, const float* __restrict__ v2,
                          float* __restrict__ a1, float* __restrict__ a2) {
  int g = blockIdx.x * 256 + threadIdx.x;
  const float* h; const float* v; float* dst; int row;
  if (g < NU) { h = hU; v = v1; dst = a1; row = g; }
  else        { h = hI; v = v2; dst = a2; row = g - NU; }
  const fx4* hv = (const fx4*)(h + (size_t)row * DD);
  const fx4* vv = (const fx4*)v;
  float s = 0.f;
#pragma unroll
  for (int q = 0; q < DD / 4; ++q) {
    fx4 hq = hv[q], vq = vv[q];
    s += hq[0]*vq[0] + hq[1]*vq[1] + hq[2]*vq[2] + hq[3]*vq[3];
  }
  dst[row] = s;
}

// ---- K3: global max of a2 (single block, deterministic)
__global__ void k_maxa2(const float* __restrict__ a2, float* __restrict__ mx) {
  __shared__ float red[256];
  float m = -3.0e38f;
  for (int i = threadIdx.x; i < NI; i += 256) m = fmaxf(m, a2[i]);
  red[threadIdx.x] = m;
  __syncthreads();
  for (int s = 128; s > 0; s >>= 1) {
    if (threadIdx.x < s) red[threadIdx.x] = fmaxf(red[threadIdx.x], red[threadIdx.x + s]);
    __syncthreads();
  }
  if (threadIdx.x == 0) mx[0] = red[0];
}

// ---- K4: WiT[k][i] (bf16) = Wi[i][k] = sum_j h_i[i][j]*W[k][j]
// 128 blocks x 256 thr; block owns 64 rows of h_i; thread tile 4 rows x 8 cols.
__global__ __launch_bounds__(256) void k_wit(const float* __restrict__ hI,
                                             const float* __restrict__ W,
                                             short* __restrict__ WiT) {
  __shared__ float Wl[128 * 128];
  const int tid = threadIdx.x;
#pragma unroll
  for (int it = 0; it < 16; ++it) {
    int idx = it * 1024 + tid * 4;
    *(fx4*)(Wl + idx) = *(const fx4*)(W + idx);
  }
  __syncthreads();
  const int i0 = blockIdx.x * 64;
  const int rg = tid & 15;   // 16 row groups x 4 rows
  const int kg = tid >> 4;   // 16 col groups x 8 cols
  const int r0 = i0 + rg * 4;
  const int k0 = kg * 8;
  float acc[4][8];
#pragma unroll
  for (int r = 0; r < 4; ++r)
#pragma unroll
    for (int c = 0; c < 8; ++c) acc[r][c] = 0.f;
  for (int j = 0; j < 128; j += 4) {
    fx4 wv[8], hv[4];
#pragma unroll
    for (int c = 0; c < 8; ++c) wv[c] = *(const fx4*)(Wl + (k0 + c) * 128 + j);
#pragma unroll
    for (int r = 0; r < 4; ++r) hv[r] = *(const fx4*)(hI + (size_t)(r0 + r) * DD + j);
#pragma unroll
    for (int r = 0; r < 4; ++r)
#pragma unroll
      for (int c = 0; c < 8; ++c)
        acc[r][c] += hv[r][0]*wv[c][0] + hv[r][1]*wv[c][1] + hv[r][2]*wv[c][2] + hv[r][3]*wv[c][3];
  }
#pragma unroll
  for (int c = 0; c < 8; ++c) {
    sx4 pk;
#pragma unroll
    for (int r = 0; r < 4; ++r) pk[r] = f2bf(acc[r][c]);
    *(sx4*)(WiT + (size_t)(k0 + c) * NI + r0) = pk;
  }
}

// ---- K5: fused masked-softmax + alpha write + out = alpha@Wi (MFMA)
// grid 256 x 512 thr (8 waves). Block owns 32 u-rows.
__global__ __launch_bounds__(512, 2) void k_main(
    const int* __restrict__ adj, const float* __restrict__ a1g,
    const float* __restrict__ a2g, const float* __restrict__ mxp,
    const short* __restrict__ WiT, float* __restrict__ outp,
    float* __restrict__ alphap)
{
  __shared__ __align__(16) char smem[65536];
  unsigned char* bytesl = (unsigned char*)smem;     // [32] rows, stride 1026 (bank-spread) = 32832 B
  float* Crow  = (float*)(smem + 32832);            // [32]
  float* a1l   = (float*)(smem + 32960);            // [32]
  float* rinvl = (float*)(smem + 33088);            // [32]
  float* lpart = (float*)(smem + 33216);            // [32][8]
  const int tid  = threadIdx.x;
  const int lane = tid & 63;
  const int wvid = tid >> 6;
  const int u0 = blockIdx.x * 32;
  const float mA2 = mxp[0];
  if (tid < 32) {
    float av = a1g[u0 + tid];
    a1l[tid]  = av;
    Crow[tid] = lrelu(av + mA2);   // valid softmax shift: >= masked row max
  }
  // this thread's 16 a2 values (fixed i-set for the whole phase A)
  float a2r[16];
  {
    const fx4 q0 = *(const fx4*)(a2g + tid * 8);
    const fx4 q1 = *(const fx4*)(a2g + tid * 8 + 4);
    const fx4 q2 = *(const fx4*)(a2g + 4096 + tid * 8);
    const fx4 q3 = *(const fx4*)(a2g + 4096 + tid * 8 + 4);
#pragma unroll
    for (int e = 0; e < 4; ++e) {
      a2r[e] = q0[e]; a2r[4+e] = q1[e]; a2r[8+e] = q2[e]; a2r[12+e] = q3[e];
    }
  }
  __syncthreads();

  // ---- Phase A: one pass over adj rows -> l_u and LDS bitmask ----
  for (int r = 0; r < 32; ++r) {
    const float a1u = a1l[r];
    const float Cr  = Crow[r];
    const size_t rowbase = (size_t)(u0 + r) * NI;
    float ps = 0.f;
#pragma unroll
    for (int it = 0; it < 2; ++it) {
      const int ibase = it * 4096 + tid * 8;
      ix4 m0 = *(const ix4*)(adj + rowbase + ibase);
      ix4 m1 = *(const ix4*)(adj + rowbase + ibase + 4);
      unsigned byte = 0u;
#pragma unroll
      for (int e = 0; e < 8; ++e) {
        int mv = (e < 4) ? m0[e] : m1[e - 4];
        float p = __expf(lrelu(a1u + a2r[it * 8 + e]) - Cr);
        if (mv != 0) { ps += p; byte |= (1u << e); }
      }
      bytesl[r * 1026 + it * 512 + tid] = (unsigned char)byte;
    }
#pragma unroll
    for (int s = 1; s < 64; s <<= 1) ps += __shfl_xor(ps, s, 64);
    if (lane == 0) lpart[r * 8 + wvid] = ps;
  }
  __syncthreads();
  if (tid < 32) {
    float l = 0.f;
#pragma unroll
    for (int w = 0; w < 8; ++w) l += lpart[tid * 8 + w];
    rinvl[tid] = (l > 0.f) ? (1.f / l) : 0.f;
  }
  __syncthreads();

  // ---- Phase B: alpha writes + MFMA accumulate; 8 waves = 2 row-tiles x shared, k-phase = wvid ----
  const int lr = lane & 15;
  const int lg = lane >> 4;
  const float A10 = a1l[lr],      C0 = Crow[lr],      ri0 = rinvl[lr];
  const float A11 = a1l[16 + lr], C1 = Crow[16 + lr], ri1 = rinvl[16 + lr];
  const size_t arow0 = (size_t)(u0 + lr) * NI;
  const size_t arow1 = (size_t)(u0 + 16 + lr) * NI;
  fx4 acc[2][8];
#pragma unroll
  for (int t = 0; t < 2; ++t)
#pragma unroll
    for (int n = 0; n < 8; ++n) acc[t][n] = (fx4){0.f, 0.f, 0.f, 0.f};

  for (int m = 0; m < 32; ++m) {
    const int ks = wvid + (m << 3);        // k-step 0..255, wave-phase interleaved
    const int ibase = ks * 32;
    const int io = ibase + lg * 8;
    bx8 bfr[8];
#pragma unroll
    for (int n = 0; n < 8; ++n)
      bfr[n] = *(const bx8*)(WiT + (size_t)(n * 16 + lr) * NI + io);
    const unsigned by0 = bytesl[lr * 1026 + ks * 4 + lg];
    const unsigned by1 = bytesl[(16 + lr) * 1026 + ks * 4 + lg];
    const fx4 aq0 = *(const fx4*)(a2g + io);
    const fx4 aq1 = *(const fx4*)(a2g + io + 4);
    float p0[8], p1[8];
#pragma unroll
    for (int j = 0; j < 8; ++j) {
      const float a2v = (j < 4) ? aq0[j] : aq1[j - 4];
      float e0 = __expf(lrelu(A10 + a2v) - C0);
      float e1 = __expf(lrelu(A11 + a2v) - C1);
      p0[j] = ((by0 >> j) & 1u) ? e0 : 0.f;
      p1[j] = ((by1 >> j) & 1u) ? e1 : 0.f;
    }
    fx4 s0, s1, s2, s3;
#pragma unroll
    for (int j = 0; j < 4; ++j) {
      s0[j] = p0[j] * ri0; s1[j] = p0[4 + j] * ri0;
      s2[j] = p1[j] * ri1; s3[j] = p1[4 + j] * ri1;
    }
    *(fx4*)(alphap + arow0 + io)     = s0;
    *(fx4*)(alphap + arow0 + io + 4) = s1;
    *(fx4*)(alphap + arow1 + io)     = s2;
    *(fx4*)(alphap + arow1 + io + 4) = s3;
    bx8 af0, af1;
#pragma unroll
    for (int j = 0; j < 8; ++j) { af0[j] = f2bf(p0[j]); af1[j] = f2bf(p1[j]); }
#pragma unroll
    for (int n = 0; n < 8; ++n) {
      acc[0][n] = __builtin_amdgcn_mfma_f32_16x16x32_bf16(af0, bfr[n], acc[0][n], 0, 0, 0);
      acc[1][n] = __builtin_amdgcn_mfma_f32_16x16x32_bf16(af1, bfr[n], acc[1][n], 0, 0, 0);
    }
  }

  // ---- Epilogue: reduce 8 wave-partials (4 LDS copies), scale by 1/l, store out ----
  const float ri_fin = rinvl[tid >> 4];
  __syncthreads();                       // all phase-B reads of smem done
  float* cop = (float*)smem;             // 4 copies of [32][128] f32 = 64 KB
  float* my  = cop + (size_t)(wvid & 3) * 4096;
  if (wvid < 4) {
#pragma unroll
    for (int t = 0; t < 2; ++t)
#pragma unroll
      for (int n = 0; n < 8; ++n)
#pragma unroll
        for (int v = 0; v < 4; ++v)
          my[(t * 16 + lg * 4 + v) * 128 + n * 16 + lr] = acc[t][n][v];
  }
  __syncthreads();
  if (wvid >= 4) {
#pragma unroll
    for (int t = 0; t < 2; ++t)
#pragma unroll
      for (int n = 0; n < 8; ++n)
#pragma unroll
        for (int v = 0; v < 4; ++v)
          my[(t * 16 + lg * 4 + v) * 128 + n * 16 + lr] += acc[t][n][v];
  }
  __syncthreads();
  {
    const int r  = tid >> 4;
    const int c0 = (tid & 15) * 8;
    fx4 o0, o1;
#pragma unroll
    for (int e = 0; e < 4; ++e) {
      int cA = c0 + e, cB = c0 + 4 + e;
      o0[e] = (cop[r*128+cA] + cop[4096 + r*128+cA] + cop[8192 + r*128+cA] + cop[12288 + r*128+cA]) * ri_fin;
      o1[e] = (cop[r*128+cB] + cop[4096 + r*128+cB] + cop[8192 + r*128+cB] + cop[12288 + r*128+cB]) * ri_fin;
    }
    *(fx4*)(outp + (size_t)(u0 + r) * DD + c0)     = o0;
    *(fx4*)(outp + (size_t)(u0 + r) * DD + c0 + 4) = o1;
  }
}

extern "C" void kernel_launch(void* const* d_in, const int* in_sizes, int n_in,
                              void* d_out, int out_size, void* d_ws, size_t ws_size,
                              hipStream_t stream) {
  (void)in_sizes; (void)n_in; (void)out_size; (void)ws_size;
  const float* h_u = (const float*)d_in[0];
  const float* h_i = (const float*)d_in[1];
  const int*   adj = (const int*)d_in[2];
  const float* W   = (const float*)d_in[3];
  const float* a   = (const float*)d_in[4];

  float* outp   = (float*)d_out;                       // [8192][128]
  float* alphap = (float*)d_out + (size_t)NU * DD;     // [8192][8192]

  char* ws = (char*)d_ws;
  float* v1  = (float*)(ws + 0);        // 128 f32
  float* v2  = (float*)(ws + 512);      // 128 f32
  float* mx  = (float*)(ws + 1024);     // 1 f32
  float* a1  = (float*)(ws + 4096);     // 8192 f32
  float* a2  = (float*)(ws + 36864);    // 8192 f32
  short* WiT = (short*)(ws + 131072);   // 128*8192 bf16 = 2 MiB

  k_vecs   <<<1,   128, 0, stream>>>(W, a, v1, v2);
  k_rowdots<<<64,  256, 0, stream>>>(h_u, h_i, v1, v2, a1, a2);
  k_maxa2  <<<1,   256, 0, stream>>>(a2, mx);
  k_wit    <<<128, 256, 0, stream>>>(h_i, W, WiT);
  k_main   <<<256, 512, 0, stream>>>(adj, a1, a2, mx, WiT, outp, alphap);
}

// Round 2
// 226.022 us; speedup vs baseline: 1.1472x; 1.1472x over previous
//
#include <hip/hip_runtime.h>

#define NU 8192
#define NI 8192
#define DD 128
#define ROWS 16

typedef float fx4 __attribute__((ext_vector_type(4)));
typedef int   ix4 __attribute__((ext_vector_type(4)));
typedef short bx8 __attribute__((ext_vector_type(8)));
typedef short sx4 __attribute__((ext_vector_type(4)));

__device__ __forceinline__ short f2bf(float f) {
  unsigned u = __float_as_uint(f);
  u = (u + 0x7FFFu + ((u >> 16) & 1u)) >> 16;   // RNE f32 -> bf16
  return (short)u;
}

__device__ __forceinline__ float lrelu(float x) { return fmaxf(x, 0.2f * x); }

// ---- K1: v1[j] = sum_k a[k]*W[k][j] ; v2[j] = sum_k a[128+k]*W[k][j]
__global__ void k_vecs(const float* __restrict__ W, const float* __restrict__ a,
                       float* __restrict__ v1, float* __restrict__ v2) {
  int j = threadIdx.x;  // 128 threads
  float s1 = 0.f, s2 = 0.f;
  for (int k = 0; k < DD; ++k) {
    float w = W[k * DD + j];
    s1 += a[k] * w;
    s2 += a[DD + k] * w;
  }
  v1[j] = s1; v2[j] = s2;
}

// ---- K2: a1[u] = h_u[u]·v1 ; a2[i] = h_i[i]·v2
__global__ void k_rowdots(const float* __restrict__ hU, const float* __restrict__ hI,
                          const float* __restrict__ v1, const float* __restrict__ v2,
                          float* __restrict__ a1, float* __restrict__ a2) {
  int g = blockIdx.x * 256 + threadIdx.x;
  const float* h; const float* v; float* dst; int row;
  if (g < NU) { h = hU; v = v1; dst = a1; row = g; }
  else        { h = hI; v = v2; dst = a2; row = g - NU; }
  const fx4* hv = (const fx4*)(h + (size_t)row * DD);
  const fx4* vv = (const fx4*)v;
  float s = 0.f;
#pragma unroll
  for (int q = 0; q < DD / 4; ++q) {
    fx4 hq = hv[q], vq = vv[q];
    s += hq[0]*vq[0] + hq[1]*vq[1] + hq[2]*vq[2] + hq[3]*vq[3];
  }
  dst[row] = s;
}

// ---- K3: global max of a2 (single block, deterministic)
__global__ void k_maxa2(const float* __restrict__ a2, float* __restrict__ mx) {
  __shared__ float red[256];
  float m = -3.0e38f;
  for (int i = threadIdx.x; i < NI; i += 256) m = fmaxf(m, a2[i]);
  red[threadIdx.x] = m;
  __syncthreads();
  for (int s = 128; s > 0; s >>= 1) {
    if (threadIdx.x < s) red[threadIdx.x] = fmaxf(red[threadIdx.x], red[threadIdx.x + s]);
    __syncthreads();
  }
  if (threadIdx.x == 0) mx[0] = red[0];
}

// ---- K4: WiT[k][i] (bf16) = Wi[i][k] = sum_j h_i[i][j]*W[k][j]
__global__ __launch_bounds__(256) void k_wit(const float* __restrict__ hI,
                                             const float* __restrict__ W,
                                             short* __restrict__ WiT) {
  __shared__ float Wl[128 * 128];
  const int tid = threadIdx.x;
#pragma unroll
  for (int it = 0; it < 16; ++it) {
    int idx = it * 1024 + tid * 4;
    *(fx4*)(Wl + idx) = *(const fx4*)(W + idx);
  }
  __syncthreads();
  const int i0 = blockIdx.x * 64;
  const int rg = tid & 15;
  const int kg = tid >> 4;
  const int r0 = i0 + rg * 4;
  const int k0 = kg * 8;
  float acc[4][8];
#pragma unroll
  for (int r = 0; r < 4; ++r)
#pragma unroll
    for (int c = 0; c < 8; ++c) acc[r][c] = 0.f;
  for (int j = 0; j < 128; j += 4) {
    fx4 wv[8], hv[4];
#pragma unroll
    for (int c = 0; c < 8; ++c) wv[c] = *(const fx4*)(Wl + (k0 + c) * 128 + j);
#pragma unroll
    for (int r = 0; r < 4; ++r) hv[r] = *(const fx4*)(hI + (size_t)(r0 + r) * DD + j);
#pragma unroll
    for (int r = 0; r < 4; ++r)
#pragma unroll
      for (int c = 0; c < 8; ++c)
        acc[r][c] += hv[r][0]*wv[c][0] + hv[r][1]*wv[c][1] + hv[r][2]*wv[c][2] + hv[r][3]*wv[c][3];
  }
#pragma unroll
  for (int c = 0; c < 8; ++c) {
    sx4 pk;
#pragma unroll
    for (int r = 0; r < 4; ++r) pk[r] = f2bf(acc[r][c]);
    *(sx4*)(WiT + (size_t)(k0 + c) * NI + r0) = pk;
  }
}

// ---- K5: fused masked-softmax + alpha write + out = alpha@Wi (MFMA)
// grid 512 x 512 thr (8 waves). Block owns 16 u-rows. ~35 KB LDS.
__global__ __launch_bounds__(512, 4) void k_main(
    const int* __restrict__ adj, const float* __restrict__ a1g,
    const float* __restrict__ a2g, const float* __restrict__ mxp,
    const short* __restrict__ WiT, float* __restrict__ outp,
    float* __restrict__ alphap)
{
  __shared__ __align__(16) char smem[34560];
  unsigned char* bytesl = (unsigned char*)smem;  // [16] rows x 1028 stride (phase A/B)
  float* cop   = (float*)smem;                   // epilogue: 4 copies x [16][132] f32 = 33792 B (reuse)
  float* Crow  = (float*)(smem + 33792);         // [16]
  float* a1l   = (float*)(smem + 33856);         // [16]
  float* rinvl = (float*)(smem + 33920);         // [16]
  float* lpart = (float*)(smem + 33984);         // [16][8]

  const int tid  = threadIdx.x;
  const int lane = tid & 63;
  const int wvid = tid >> 6;
  const int u0 = blockIdx.x * ROWS;
  const float mA2 = mxp[0];
  if (tid < ROWS) {
    float av = a1g[u0 + tid];
    a1l[tid]  = av;
    Crow[tid] = lrelu(av + mA2);   // valid softmax shift: >= masked row max
  }
  // this thread's 16 a2 values (i = it*4096 + tid*8 + e)
  float a2r[16];
  {
    const fx4 q0 = *(const fx4*)(a2g + tid * 8);
    const fx4 q1 = *(const fx4*)(a2g + tid * 8 + 4);
    const fx4 q2 = *(const fx4*)(a2g + 4096 + tid * 8);
    const fx4 q3 = *(const fx4*)(a2g + 4096 + tid * 8 + 4);
#pragma unroll
    for (int e = 0; e < 4; ++e) {
      a2r[e] = q0[e]; a2r[4+e] = q1[e]; a2r[8+e] = q2[e]; a2r[12+e] = q3[e];
    }
  }
  __syncthreads();

  // ---- Phase A: one nontemporal pass over adj rows -> l_u and LDS bitmask ----
  for (int r = 0; r < ROWS; ++r) {
    const float a1u = a1l[r];
    const float Cr  = Crow[r];
    const size_t rowbase = (size_t)(u0 + r) * NI;
    float ps = 0.f;
#pragma unroll
    for (int it = 0; it < 2; ++it) {
      const int ibase = it * 4096 + tid * 8;
      ix4 m0 = __builtin_nontemporal_load((const ix4*)(adj + rowbase + ibase));
      ix4 m1 = __builtin_nontemporal_load((const ix4*)(adj + rowbase + ibase + 4));
      unsigned byte = 0u;
#pragma unroll
      for (int e = 0; e < 8; ++e) {
        int mv = (e < 4) ? m0[e] : m1[e - 4];
        float p = __expf(lrelu(a1u + a2r[it * 8 + e]) - Cr);
        if (mv != 0) { ps += p; byte |= (1u << e); }
      }
      bytesl[r * 1028 + it * 512 + tid] = (unsigned char)byte;
    }
#pragma unroll
    for (int s = 1; s < 64; s <<= 1) ps += __shfl_xor(ps, s, 64);
    if (lane == 0) lpart[r * 8 + wvid] = ps;
  }
  __syncthreads();
  if (tid < ROWS) {
    float l = 0.f;
#pragma unroll
    for (int w = 0; w < 8; ++w) l += lpart[tid * 8 + w];
    rinvl[tid] = (l > 0.f) ? (1.f / l) : 0.f;
  }
  __syncthreads();

  // ---- Phase B: alpha writes + MFMA; 8 waves k-phase-split over 256 k-steps ----
  const int lr = lane & 15;
  const int lg = lane >> 4;
  const float A1 = a1l[lr], C = Crow[lr], ri = rinvl[lr];
  const size_t arow = (size_t)(u0 + lr) * NI;
  fx4 acc[8];
#pragma unroll
  for (int n = 0; n < 8; ++n) acc[n] = (fx4){0.f, 0.f, 0.f, 0.f};

  for (int m = 0; m < 32; ++m) {
    const int ks = wvid + (m << 3);        // 0..255
    const int io = ks * 32 + lg * 8;
    bx8 bfr[8];
#pragma unroll
    for (int n = 0; n < 8; ++n)
      bfr[n] = *(const bx8*)(WiT + (size_t)(n * 16 + lr) * NI + io);
    const unsigned wmask = *(const unsigned*)(bytesl + lr * 1028 + ks * 4);
    const unsigned by = (wmask >> (lg * 8)) & 0xFFu;
    const fx4 aq0 = *(const fx4*)(a2g + io);
    const fx4 aq1 = *(const fx4*)(a2g + io + 4);
    float p[8];
#pragma unroll
    for (int j = 0; j < 8; ++j) {
      const float a2v = (j < 4) ? aq0[j] : aq1[j - 4];
      float e0 = __expf(lrelu(A1 + a2v) - C);
      p[j] = ((by >> j) & 1u) ? e0 : 0.f;
    }
    fx4 s0, s1;
#pragma unroll
    for (int j = 0; j < 4; ++j) { s0[j] = p[j] * ri; s1[j] = p[4 + j] * ri; }
    __builtin_nontemporal_store(s0, (fx4*)(alphap + arow + io));
    __builtin_nontemporal_store(s1, (fx4*)(alphap + arow + io + 4));
    bx8 af;
#pragma unroll
    for (int j = 0; j < 8; ++j) af[j] = f2bf(p[j]);
#pragma unroll
    for (int n = 0; n < 8; ++n)
      acc[n] = __builtin_amdgcn_mfma_f32_16x16x32_bf16(af, bfr[n], acc[n], 0, 0, 0);
  }

  // ---- Epilogue: reduce 8 wave-partials via 4 LDS copies (stride-132 pad) ----
  const float ri_fin = rinvl[tid >> 5];
  __syncthreads();                       // all phase-B LDS reads done
  float* my = cop + (size_t)(wvid & 3) * 2112;
  if (wvid < 4) {
#pragma unroll
    for (int n = 0; n < 8; ++n)
#pragma unroll
      for (int v = 0; v < 4; ++v)
        my[(lg * 4 + v) * 132 + n * 16 + lr] = acc[n][v];
  }
  __syncthreads();
  if (wvid >= 4) {
#pragma unroll
    for (int n = 0; n < 8; ++n)
#pragma unroll
      for (int v = 0; v < 4; ++v)
        my[(lg * 4 + v) * 132 + n * 16 + lr] += acc[n][v];
  }
  __syncthreads();
  {
    const int r  = tid >> 5;          // 0..15
    const int c0 = (tid & 31) * 4;    // 0..124
    fx4 s = *(const fx4*)(cop + r * 132 + c0);
#pragma unroll
    for (int c = 1; c < 4; ++c) {
      fx4 t = *(const fx4*)(cop + c * 2112 + r * 132 + c0);
      s[0] += t[0]; s[1] += t[1]; s[2] += t[2]; s[3] += t[3];
    }
    fx4 o;
#pragma unroll
    for (int e = 0; e < 4; ++e) o[e] = s[e] * ri_fin;
    *(fx4*)(outp + (size_t)(u0 + r) * DD + c0) = o;
  }
}

extern "C" void kernel_launch(void* const* d_in, const int* in_sizes, int n_in,
                              void* d_out, int out_size, void* d_ws, size_t ws_size,
                              hipStream_t stream) {
  (void)in_sizes; (void)n_in; (void)out_size; (void)ws_size;
  const float* h_u = (const float*)d_in[0];
  const float* h_i = (const float*)d_in[1];
  const int*   adj = (const int*)d_in[2];
  const float* W   = (const float*)d_in[3];
  const float* a   = (const float*)d_in[4];

  float* outp   = (float*)d_out;                       // [8192][128]
  float* alphap = (float*)d_out + (size_t)NU * DD;     // [8192][8192]

  char* ws = (char*)d_ws;
  float* v1  = (float*)(ws + 0);        // 128 f32
  float* v2  = (float*)(ws + 512);      // 128 f32
  float* mx  = (float*)(ws + 1024);     // 1 f32
  float* a1  = (float*)(ws + 4096);     // 8192 f32
  float* a2  = (float*)(ws + 36864);    // 8192 f32
  short* WiT = (short*)(ws + 131072);   // 128*8192 bf16 = 2 MiB

  k_vecs   <<<1,   128, 0, stream>>>(W, a, v1, v2);
  k_rowdots<<<64,  256, 0, stream>>>(h_u, h_i, v1, v2, a1, a2);
  k_maxa2  <<<1,   256, 0, stream>>>(a2, mx);
  k_wit    <<<128, 256, 0, stream>>>(h_i, W, WiT);
  k_main   <<<512, 512, 0, stream>>>(adj, a1, a2, mx, WiT, outp, alphap);
}